// Round 1
// baseline (161.546 us; speedup 1.0000x reference)
//
#include <hip/hip_runtime.h>

// YOLOv1 loss on MI355X.
// Inputs (setup_inputs order):
//   d_in[0] bounding_boxes: (16384,12,12,12) f32   — [x1,y1,w1,h1,c1, x2,y2,w2,h2,c2, cls0,cls1]
//   d_in[1] ground_truth:   (16384,12,12,1,12) f32 — [x,y,w,h,conf, l,u,r,d, obj, cls0,cls1]
//   d_in[2] grid_size: int scalar (8)
//   d_in[3] img_size:  int scalar (96)
// Output: 6 f32 scalars: loss, l_coord, loss_confidence, l_cls, iou_sum, object_num

#define S_DIM 12
#define CELLS_PER_IMG (S_DIM * S_DIM)   // 144
#define BATCH_N 16384
#define NCELLS (BATCH_N * CELLS_PER_IMG) // 2,359,296
#define L_COORD_C 5.0f
#define L_NOOBJ_C 0.5f

__device__ __forceinline__ float sq_sqrt(float t) {
    return sqrtf(fmaxf(t, 0.0f) + 1e-08f);
}

__global__ __launch_bounds__(256) void yolo_loss_main(
    const float* __restrict__ bb,
    const float* __restrict__ gt,
    const int* __restrict__ gs_p,
    const int* __restrict__ im_p,
    float* __restrict__ out)
{
    const float gs = (float)(*gs_p);
    const float im = (float)(*im_p);
    const float im1 = im - 1.0f;

    float s_conf = 0.0f;  // l_no_other + l_no_sel + l_conf_obj
    float s_coord = 0.0f;
    float s_cls = 0.0f;
    float s_iou = 0.0f;
    float s_obj = 0.0f;

    const int tid = blockIdx.x * blockDim.x + threadIdx.x;
    const int stride = gridDim.x * blockDim.x;

    for (int n = tid; n < NCELLS; n += stride) {
        const float4* bb4 = (const float4*)(bb + (size_t)n * 12);
        const float4* gt4 = (const float4*)(gt + (size_t)n * 12);
        float4 b0 = bb4[0];   // x1,y1,w1,h1
        float4 b1 = bb4[1];   // c1,x2,y2,w2
        float4 b2 = bb4[2];   // h2,c2,cls0,cls1
        float4 g0 = gt4[0];   // x,y,w,h
        float4 g1 = gt4[1];   // conf, l, u, r
        float4 g2 = gt4[2];   // d, obj, cls0, cls1

        const float c1 = b1.x;
        const float c2 = b2.y;
        const bool sel2 = c1 < c2;

        const float p0 = sel2 ? b1.y : b0.x;
        const float p1 = sel2 ? b1.z : b0.y;
        const float p2 = sel2 ? b1.w : b0.z;
        const float p3 = sel2 ? b2.x : b0.w;
        const float p4 = sel2 ? c2   : c1;   // sel_conf
        const float other = sel2 ? c1 : c2;  // other_conf

        const bool obj = (g2.y != 0.0f);
        const float objf = obj ? 1.0f : 0.0f;

        // confidence losses
        float conf_c = L_NOOBJ_C * other * other;                 // l_no_other (all cells)
        const float dconf = g1.x - p4;
        conf_c += obj ? (dconf * dconf) : (L_NOOBJ_C * p4 * p4);  // obj / noobj term
        s_conf += conf_c;

        // coord loss
        const float dx = g0.x - p0;
        const float dy = g0.y - p1;
        const float dw = sq_sqrt(g0.z) - sq_sqrt(p2);
        const float dh = sq_sqrt(g0.w) - sq_sqrt(p3);
        s_coord += objf * (L_COORD_C * (dx*dx + dy*dy + dw*dw + dh*dh));

        // class loss
        const float dc0 = g2.z - b2.z;
        const float dc1 = g2.w - b2.w;
        s_cls += objf * (dc0*dc0 + dc1*dc1);

        // IoU
        const int rem = n % CELLS_PER_IMG;
        const int gi = rem / S_DIM;   // row -> gridY
        const int gj = rem % S_DIM;   // col -> gridX
        const float px = truncf((float)gj * gs + p0 * gs);
        const float py = truncf((float)gi * gs + p1 * gs);
        const float pw = truncf(p2 * im);
        const float ph = truncf(p3 * im);
        const float pl = fmaxf(0.0f, px - pw * 0.5f);
        const float pu = fmaxf(0.0f, py - ph * 0.5f);
        const float pr = fminf(im1, px + pw * 0.5f);
        const float pd = fminf(im1, py + ph * 0.5f);
        const float pA = (pr - pl) * (pd - pu);
        const float gl = g1.y, gu = g1.z, gr = g1.w, gd = g2.x;
        const float gA = (gr - gl) * (gd - gu);
        const float lx = fmaxf(pl, gl);
        const float rx = fminf(pr, gr);
        const float uy = fmaxf(pu, gu);
        const float dy2 = fminf(pd, gd);
        const float inter = (rx - lx) * (dy2 - uy);
        const float iou = ((rx < lx) || (dy2 < uy)) ? 0.0f : inter / (pA + gA - inter);
        s_iou += objf * iou;

        s_obj += objf;
    }

    // wave (64-lane) reduction
    #pragma unroll
    for (int off = 32; off > 0; off >>= 1) {
        s_conf  += __shfl_down(s_conf,  off);
        s_coord += __shfl_down(s_coord, off);
        s_cls   += __shfl_down(s_cls,   off);
        s_iou   += __shfl_down(s_iou,   off);
        s_obj   += __shfl_down(s_obj,   off);
    }

    __shared__ float red[4][5];
    const int wave = threadIdx.x >> 6;
    const int lane = threadIdx.x & 63;
    if (lane == 0) {
        red[wave][0] = s_conf;
        red[wave][1] = s_coord;
        red[wave][2] = s_cls;
        red[wave][3] = s_iou;
        red[wave][4] = s_obj;
    }
    __syncthreads();
    if (threadIdx.x == 0) {
        float t0 = 0, t1 = 0, t2 = 0, t3 = 0, t4 = 0;
        #pragma unroll
        for (int w = 0; w < 4; ++w) {
            t0 += red[w][0]; t1 += red[w][1]; t2 += red[w][2];
            t3 += red[w][3]; t4 += red[w][4];
        }
        atomicAdd(&out[2], t0);  // loss_confidence
        atomicAdd(&out[1], t1);  // l_coord
        atomicAdd(&out[3], t2);  // l_cls
        atomicAdd(&out[4], t3);  // iou_sum
        atomicAdd(&out[5], t4);  // object_num
    }
}

__global__ void yolo_loss_finalize(float* __restrict__ out) {
    // loss = l_no_other + l_no_sel + l_coord + l_conf_obj + l_cls
    //      = loss_confidence + l_coord + l_cls
    out[0] = out[1] + out[2] + out[3];
}

extern "C" void kernel_launch(void* const* d_in, const int* in_sizes, int n_in,
                              void* d_out, int out_size, void* d_ws, size_t ws_size,
                              hipStream_t stream) {
    const float* bb = (const float*)d_in[0];
    const float* gt = (const float*)d_in[1];
    const int* gs_p = (const int*)d_in[2];
    const int* im_p = (const int*)d_in[3];
    float* out = (float*)d_out;

    hipMemsetAsync(d_out, 0, 6 * sizeof(float), stream);

    const int block = 256;
    const int grid = 2048;  // grid-stride over 2.36M cells (~4.5 cells/thread)
    yolo_loss_main<<<grid, block, 0, stream>>>(bb, gt, gs_p, im_p, out);
    yolo_loss_finalize<<<1, 1, 0, stream>>>(out);
}

// Round 2
// 127.302 us; speedup vs baseline: 1.2690x; 1.2690x over previous
//
#include <hip/hip_runtime.h>

// YOLOv1 loss on MI355X — coalesced LDS-staged version.
// Inputs (setup_inputs order):
//   d_in[0] bounding_boxes: (16384,12,12,12) f32   — [x1,y1,w1,h1,c1, x2,y2,w2,h2,c2, cls0,cls1]
//   d_in[1] ground_truth:   (16384,12,12,1,12) f32 — [x,y,w,h,conf, l,u,r,d, obj, cls0,cls1]
//   d_in[2] grid_size: int scalar (8)
//   d_in[3] img_size:  int scalar (96)
// Output: 6 f32 scalars: loss, l_coord, loss_confidence, l_cls, iou_sum, object_num

#define S_DIM 12
#define CELLS_PER_IMG (S_DIM * S_DIM)      // 144
#define BATCH_N 16384
#define NCELLS (BATCH_N * CELLS_PER_IMG)   // 2,359,296
#define TILE 256                            // cells per block-iteration
#define F4_PER_TILE (TILE * 3)              // 768 float4 per input array
#define NTILES (NCELLS / TILE)              // 9216 (exact)
#define GRID_BLKS 1536                      // 6 blocks/CU (LDS-bound), 6 tiles/block exact
#define L_COORD_C 5.0f
#define L_NOOBJ_C 0.5f

__device__ __forceinline__ float sq_sqrt(float t) {
    return sqrtf(fmaxf(t, 0.0f) + 1e-08f);
}

// XOR-swizzle on the float4 slot index. Injective (XORs bits 4..6 into 0..2).
// Applied identically on write and read -> correctness independent of the
// exact mask; kills the 8-way bank conflict of the stride-12-word cell reads.
__device__ __forceinline__ int swz(int s) { return s ^ ((s >> 4) & 7); }

__global__ __launch_bounds__(256, 6) void yolo_loss_main(
    const float4* __restrict__ bb4,
    const float4* __restrict__ gt4,
    const int* __restrict__ gs_p,
    const int* __restrict__ im_p,
    float* __restrict__ out)
{
    __shared__ float4 sb[F4_PER_TILE];   // 12 KB
    __shared__ float4 sg[F4_PER_TILE];   // 12 KB
    __shared__ float red[4][5];

    const float gs = (float)(*gs_p);
    const float im = (float)(*im_p);
    const float im1 = im - 1.0f;

    float s_conf = 0.0f, s_coord = 0.0f, s_cls = 0.0f, s_iou = 0.0f, s_obj = 0.0f;

    const int t = threadIdx.x;

    // prefetch tile 0
    int tile = blockIdx.x;
    float4 rb0, rb1, rb2, rg0, rg1, rg2;
    {
        const size_t tb = (size_t)tile * F4_PER_TILE;
        rb0 = bb4[tb + t]; rb1 = bb4[tb + 256 + t]; rb2 = bb4[tb + 512 + t];
        rg0 = gt4[tb + t]; rg1 = gt4[tb + 256 + t]; rg2 = gt4[tb + 512 + t];
    }

    while (tile < NTILES) {
        __syncthreads();   // prior iteration's LDS reads complete before overwrite
        sb[swz(t)]       = rb0;
        sb[swz(256 + t)] = rb1;
        sb[swz(512 + t)] = rb2;
        sg[swz(t)]       = rg0;
        sg[swz(256 + t)] = rg1;
        sg[swz(512 + t)] = rg2;
        __syncthreads();

        const int next = tile + GRID_BLKS;
        if (next < NTILES) {   // issue next tile's loads early; latency hides under compute
            const size_t tb = (size_t)next * F4_PER_TILE;
            rb0 = bb4[tb + t]; rb1 = bb4[tb + 256 + t]; rb2 = bb4[tb + 512 + t];
            rg0 = gt4[tb + t]; rg1 = gt4[tb + 256 + t]; rg2 = gt4[tb + 512 + t];
        }

        // this thread's cell
        const float4 b0 = sb[swz(3 * t)];       // x1,y1,w1,h1
        const float4 b1 = sb[swz(3 * t + 1)];   // c1,x2,y2,w2
        const float4 b2 = sb[swz(3 * t + 2)];   // h2,c2,cls0,cls1
        const float4 g0 = sg[swz(3 * t)];       // x,y,w,h
        const float4 g1 = sg[swz(3 * t + 1)];   // conf,l,u,r
        const float4 g2 = sg[swz(3 * t + 2)];   // d,obj,cls0,cls1

        const float c1 = b1.x;
        const float c2 = b2.y;
        const bool sel2 = c1 < c2;

        const float p0 = sel2 ? b1.y : b0.x;
        const float p1 = sel2 ? b1.z : b0.y;
        const float p2 = sel2 ? b1.w : b0.z;
        const float p3 = sel2 ? b2.x : b0.w;
        const float p4 = sel2 ? c2   : c1;    // sel_conf
        const float other = sel2 ? c1 : c2;   // other_conf

        const bool obj = (g2.y != 0.0f);
        const float objf = obj ? 1.0f : 0.0f;

        // confidence losses
        float conf_c = L_NOOBJ_C * other * other;
        const float dconf = g1.x - p4;
        conf_c += obj ? (dconf * dconf) : (L_NOOBJ_C * p4 * p4);
        s_conf += conf_c;

        // coord loss
        const float dx = g0.x - p0;
        const float dy = g0.y - p1;
        const float dw = sq_sqrt(g0.z) - sq_sqrt(p2);
        const float dh = sq_sqrt(g0.w) - sq_sqrt(p3);
        s_coord += objf * (L_COORD_C * (dx*dx + dy*dy + dw*dw + dh*dh));

        // class loss
        const float dc0 = g2.z - b2.z;
        const float dc1 = g2.w - b2.w;
        s_cls += objf * (dc0*dc0 + dc1*dc1);

        // IoU
        const int n = tile * TILE + t;
        const int rem = n % CELLS_PER_IMG;
        const int gi = rem / S_DIM;
        const int gj = rem % S_DIM;
        const float px = truncf((float)gj * gs + p0 * gs);
        const float py = truncf((float)gi * gs + p1 * gs);
        const float pw = truncf(p2 * im);
        const float ph = truncf(p3 * im);
        const float pl = fmaxf(0.0f, px - pw * 0.5f);
        const float pu = fmaxf(0.0f, py - ph * 0.5f);
        const float pr = fminf(im1, px + pw * 0.5f);
        const float pd = fminf(im1, py + ph * 0.5f);
        const float pA = (pr - pl) * (pd - pu);
        const float gl = g1.y, gu = g1.z, gr = g1.w, gd = g2.x;
        const float gA = (gr - gl) * (gd - gu);
        const float lx = fmaxf(pl, gl);
        const float rx = fminf(pr, gr);
        const float uy = fmaxf(pu, gu);
        const float dy2 = fminf(pd, gd);
        const float inter = (rx - lx) * (dy2 - uy);
        const float iou = ((rx < lx) || (dy2 < uy)) ? 0.0f : inter / (pA + gA - inter);
        s_iou += objf * iou;

        s_obj += objf;

        tile = next;
    }

    // wave (64-lane) reduction
    #pragma unroll
    for (int off = 32; off > 0; off >>= 1) {
        s_conf  += __shfl_down(s_conf,  off);
        s_coord += __shfl_down(s_coord, off);
        s_cls   += __shfl_down(s_cls,   off);
        s_iou   += __shfl_down(s_iou,   off);
        s_obj   += __shfl_down(s_obj,   off);
    }

    const int wave = threadIdx.x >> 6;
    const int lane = threadIdx.x & 63;
    if (lane == 0) {
        red[wave][0] = s_conf;
        red[wave][1] = s_coord;
        red[wave][2] = s_cls;
        red[wave][3] = s_iou;
        red[wave][4] = s_obj;
    }
    __syncthreads();
    if (threadIdx.x == 0) {
        float t0 = 0, t1 = 0, t2 = 0, t3 = 0, t4 = 0;
        #pragma unroll
        for (int w = 0; w < 4; ++w) {
            t0 += red[w][0]; t1 += red[w][1]; t2 += red[w][2];
            t3 += red[w][3]; t4 += red[w][4];
        }
        atomicAdd(&out[2], t0);  // loss_confidence
        atomicAdd(&out[1], t1);  // l_coord
        atomicAdd(&out[3], t2);  // l_cls
        atomicAdd(&out[4], t3);  // iou_sum
        atomicAdd(&out[5], t4);  // object_num
    }
}

__global__ void yolo_loss_finalize(float* __restrict__ out) {
    out[0] = out[1] + out[2] + out[3];
}

extern "C" void kernel_launch(void* const* d_in, const int* in_sizes, int n_in,
                              void* d_out, int out_size, void* d_ws, size_t ws_size,
                              hipStream_t stream) {
    const float4* bb4 = (const float4*)d_in[0];
    const float4* gt4 = (const float4*)d_in[1];
    const int* gs_p = (const int*)d_in[2];
    const int* im_p = (const int*)d_in[3];
    float* out = (float*)d_out;

    hipMemsetAsync(d_out, 0, 6 * sizeof(float), stream);

    yolo_loss_main<<<GRID_BLKS, 256, 0, stream>>>(bb4, gt4, gs_p, im_p, out);
    yolo_loss_finalize<<<1, 1, 0, stream>>>(out);
}

// Round 4
// 126.450 us; speedup vs baseline: 1.2775x; 1.0067x over previous
//
#include <hip/hip_runtime.h>

// YOLOv1 loss on MI355X — wave-private LDS transpose + 2-deep register
// prefetch, zero barriers in the main loop, atomics into d_out (no d_ws).
//
// Inputs (setup_inputs order):
//   d_in[0] bounding_boxes: (16384,12,12,12) f32   — [x1,y1,w1,h1,c1, x2,y2,w2,h2,c2, cls0,cls1]
//   d_in[1] ground_truth:   (16384,12,12,1,12) f32 — [x,y,w,h,conf, l,u,r,d, obj, cls0,cls1]
//   d_in[2] grid_size: int scalar (8)
//   d_in[3] img_size:  int scalar (96)
// Output: 6 f32: loss, l_coord, loss_confidence, l_cls, iou_sum, object_num

#define S_DIM 12
#define CELLS_PER_IMG (S_DIM * S_DIM)        // 144
#define NCELLS (16384 * CELLS_PER_IMG)       // 2,359,296
#define NTILES (NCELLS / 64)                 // 36,864 wave-tiles
#define GRID_BLKS 1024                       // 4 blocks/CU exact
#define WAVES 4
#define TPW 9                                // tiles/wave: 1024*4*9 = 36864 exact
#define L_COORD_C 5.0f
#define L_NOOBJ_C 0.5f

__device__ __forceinline__ float sq_sqrt(float t) {
    return sqrtf(fmaxf(t, 0.0f) + 1e-08f);
}

__global__ __launch_bounds__(256, 4) void yolo_loss_main(
    const float4* __restrict__ bb4,
    const float4* __restrict__ gt4,
    const int* __restrict__ gs_p,
    const int* __restrict__ im_p,
    float* __restrict__ out)
{
    __shared__ float4 lds[WAVES][2][192];   // 24 KB: per-wave private 2x3KB
    __shared__ float red[WAVES][5];

    const int w = threadIdx.x >> 6;
    const int l = threadIdx.x & 63;
    float4* sbb = &lds[w][0][0];
    float4* sgt = &lds[w][1][0];

    const float gs = (float)(*gs_p);
    const float im = (float)(*im_p);
    const float im1 = im - 1.0f;

    float s_conf = 0.0f, s_coord = 0.0f, s_cls = 0.0f, s_iou = 0.0f, s_obj = 0.0f;

    const int tile0 = (blockIdx.x * WAVES + w) * TPW;   // 9 consecutive tiles/wave
    const float4* pb = bb4 + (size_t)tile0 * 192;
    const float4* pg = gt4 + (size_t)tile0 * 192;

    // 2-deep prefetch: set A = tile 0, set B = tile 1 (12 float4 = 12 KB in flight)
    float4 fA0 = pb[l], fA1 = pb[64 + l], fA2 = pb[128 + l];
    float4 fAg0 = pg[l], fAg1 = pg[64 + l], fAg2 = pg[128 + l];
    float4 fB0 = pb[192 + l], fB1 = pb[256 + l], fB2 = pb[320 + l];
    float4 fBg0 = pg[192 + l], fBg1 = pg[256 + l], fBg2 = pg[320 + l];

    int rem = (tile0 * 64 + l) % CELLS_PER_IMG;   // lane's cell position in image

    #pragma unroll
    for (int i = 0; i < TPW; ++i) {
        // stage current tile from the register set of matching parity
        // (in-wave LDS ops execute in order; vmcnt waits only on this set,
        //  the other set's 6 loads stay in flight)
        if ((i & 1) == 0) {
            sbb[l] = fA0; sbb[64 + l] = fA1; sbb[128 + l] = fA2;
            sgt[l] = fAg0; sgt[64 + l] = fAg1; sgt[128 + l] = fAg2;
        } else {
            sbb[l] = fB0; sbb[64 + l] = fB1; sbb[128 + l] = fB2;
            sgt[l] = fBg0; sgt[64 + l] = fBg1; sgt[128 + l] = fBg2;
        }
        __builtin_amdgcn_sched_barrier(0);   // pin: writes before reads

        // refill the just-consumed set with tile i+2 (stays in flight ~2 tiles)
        if (i + 2 < TPW) {
            const float4* qb = pb + (size_t)(i + 2) * 192;
            const float4* qg = pg + (size_t)(i + 2) * 192;
            if ((i & 1) == 0) {
                fA0 = qb[l]; fA1 = qb[64 + l]; fA2 = qb[128 + l];
                fAg0 = qg[l]; fAg1 = qg[64 + l]; fAg2 = qg[128 + l];
            } else {
                fB0 = qb[l]; fB1 = qb[64 + l]; fB2 = qb[128 + l];
                fBg0 = qg[l]; fBg1 = qg[64 + l]; fBg2 = qg[128 + l];
            }
        }

        // this lane's cell: stride-3 float4 — lanes 0..7 hit 8 disjoint bank
        // quads (12*l mod 32 is a permutation), conflict-free; NO swizzle.
        const float4 b0 = sbb[3 * l];       // x1,y1,w1,h1
        const float4 b1 = sbb[3 * l + 1];   // c1,x2,y2,w2
        const float4 b2 = sbb[3 * l + 2];   // h2,c2,cls0,cls1
        const float4 g0 = sgt[3 * l];       // x,y,w,h
        const float4 g1 = sgt[3 * l + 1];   // conf,l,u,r
        const float4 g2 = sgt[3 * l + 2];   // d,obj,cls0,cls1
        __builtin_amdgcn_sched_barrier(0);  // pin: reads before next iter's writes

        const float c1 = b1.x;
        const float c2 = b2.y;
        const bool sel2 = c1 < c2;

        const float p0 = sel2 ? b1.y : b0.x;
        const float p1 = sel2 ? b1.z : b0.y;
        const float p2 = sel2 ? b1.w : b0.z;
        const float p3 = sel2 ? b2.x : b0.w;
        const float p4 = sel2 ? c2   : c1;    // sel_conf
        const float other = sel2 ? c1 : c2;   // other_conf

        const bool obj = (g2.y != 0.0f);
        const float objf = obj ? 1.0f : 0.0f;

        // confidence losses
        float conf_c = L_NOOBJ_C * other * other;
        const float dconf = g1.x - p4;
        conf_c += obj ? (dconf * dconf) : (L_NOOBJ_C * p4 * p4);
        s_conf += conf_c;

        // coord loss
        const float dx = g0.x - p0;
        const float dy = g0.y - p1;
        const float dw = sq_sqrt(g0.z) - sq_sqrt(p2);
        const float dh = sq_sqrt(g0.w) - sq_sqrt(p3);
        s_coord += objf * (L_COORD_C * (dx*dx + dy*dy + dw*dw + dh*dh));

        // class loss
        const float dc0 = g2.z - b2.z;
        const float dc1 = g2.w - b2.w;
        s_cls += objf * (dc0*dc0 + dc1*dc1);

        // IoU
        const int gi = rem / S_DIM;
        const int gj = rem % S_DIM;
        const float px = truncf((float)gj * gs + p0 * gs);
        const float py = truncf((float)gi * gs + p1 * gs);
        const float pw = truncf(p2 * im);
        const float ph = truncf(p3 * im);
        const float pl = fmaxf(0.0f, px - pw * 0.5f);
        const float pu = fmaxf(0.0f, py - ph * 0.5f);
        const float pr = fminf(im1, px + pw * 0.5f);
        const float pd = fminf(im1, py + ph * 0.5f);
        const float pA = (pr - pl) * (pd - pu);
        const float gl = g1.y, gu = g1.z, gr = g1.w, gd = g2.x;
        const float gA = (gr - gl) * (gd - gu);
        const float lx = fmaxf(pl, gl);
        const float rx = fminf(pr, gr);
        const float uy = fmaxf(pu, gu);
        const float dy2 = fminf(pd, gd);
        const float inter = (rx - lx) * (dy2 - uy);
        const float iou = ((rx < lx) || (dy2 < uy)) ? 0.0f : inter / (pA + gA - inter);
        s_iou += objf * iou;

        s_obj += objf;

        rem += 64;
        if (rem >= CELLS_PER_IMG) rem -= CELLS_PER_IMG;
    }

    // wave reduction
    #pragma unroll
    for (int off = 32; off > 0; off >>= 1) {
        s_conf  += __shfl_down(s_conf,  off);
        s_coord += __shfl_down(s_coord, off);
        s_cls   += __shfl_down(s_cls,   off);
        s_iou   += __shfl_down(s_iou,   off);
        s_obj   += __shfl_down(s_obj,   off);
    }

    if (l == 0) {
        red[w][0] = s_conf;
        red[w][1] = s_coord;
        red[w][2] = s_cls;
        red[w][3] = s_iou;
        red[w][4] = s_obj;
    }
    __syncthreads();   // single barrier per block, at the end
    if (threadIdx.x == 0) {
        float t0 = 0, t1 = 0, t2 = 0, t3 = 0, t4 = 0;
        #pragma unroll
        for (int v = 0; v < WAVES; ++v) {
            t0 += red[v][0]; t1 += red[v][1]; t2 += red[v][2];
            t3 += red[v][3]; t4 += red[v][4];
        }
        atomicAdd(&out[2], t0);  // loss_confidence
        atomicAdd(&out[1], t1);  // l_coord
        atomicAdd(&out[3], t2);  // l_cls
        atomicAdd(&out[4], t3);  // iou_sum
        atomicAdd(&out[5], t4);  // object_num
    }
}

__global__ void yolo_loss_finalize(float* __restrict__ out) {
    out[0] = out[1] + out[2] + out[3];
}

extern "C" void kernel_launch(void* const* d_in, const int* in_sizes, int n_in,
                              void* d_out, int out_size, void* d_ws, size_t ws_size,
                              hipStream_t stream) {
    const float4* bb4 = (const float4*)d_in[0];
    const float4* gt4 = (const float4*)d_in[1];
    const int* gs_p = (const int*)d_in[2];
    const int* im_p = (const int*)d_in[3];
    float* out = (float*)d_out;

    hipMemsetAsync(d_out, 0, 6 * sizeof(float), stream);

    yolo_loss_main<<<GRID_BLKS, 256, 0, stream>>>(bb4, gt4, gs_p, im_p, out);
    yolo_loss_finalize<<<1, 1, 0, stream>>>(out);
}